// Round 1
// baseline (67.251 us; speedup 1.0000x reference)
//
#include <hip/hip_runtime.h>

#define LEVELS 16
#define PPB    16          // points per block
#define OUTW   65          // 1 + LEVELS*4
#define BLOCK  256

__global__ __launch_bounds__(BLOCK) void grid_enc_kernel(
    const float*  __restrict__ x,
    const float4* __restrict__ data,     // [T][4] 16B entries
    const float*  __restrict__ scales,   // [16]
    const int*    __restrict__ offsets,  // [16]
    float*        __restrict__ out,      // [N][65]
    int N)
{
    __shared__ float s_out[PPB * OUTW];  // 1040 floats = 4160 B

    const int tid = threadIdx.x;
    const int p   = tid >> 4;            // local point 0..15
    const int l   = tid & 15;            // level 0..15
    const int blockStart = blockIdx.x * PPB;
    const int n = blockStart + p;

    if (n < N) {
        const float scale = scales[l];
        const int   off   = offsets[l];

        float xv = x[n];
        xv = fminf(fmaxf(xv, 0.0f), 1.0f);

        const float fx   = xv * scale;
        const float fi   = floorf(fx);
        const int   i0   = (int)fi;
        const float frac = fx - fi;      // in [0,1)

        const float4 v0 = data[off + i0];
        const float4 v1 = data[off + i0 + 1];

        const float w0 = 1.0f - frac;
        float4 r;
        r.x = w0 * v0.x + frac * v1.x;
        r.y = w0 * v0.y + frac * v1.y;
        r.z = w0 * v0.z + frac * v1.z;
        r.w = w0 * v0.w + frac * v1.w;

        const int base = p * OUTW + 1 + (l << 2);
        s_out[base + 0] = r.x;
        s_out[base + 1] = r.y;
        s_out[base + 2] = r.z;
        s_out[base + 3] = r.w;
        if (l == 0) s_out[p * OUTW] = xv;
    }
    __syncthreads();

    const int nvalid = (N - blockStart < PPB) ? (N - blockStart) : PPB;
    if (nvalid == PPB) {
        // Full block: 1040 floats = 260 float4, 16B-aligned region.
        float4* __restrict__ dst = (float4*)(out + (size_t)blockStart * OUTW);
        const float4* __restrict__ src = (const float4*)s_out;
        for (int i = tid; i < PPB * OUTW / 4; i += BLOCK) dst[i] = src[i];
    } else if (nvalid > 0) {
        float* dst = out + (size_t)blockStart * OUTW;
        for (int i = tid; i < nvalid * OUTW; i += BLOCK) dst[i] = s_out[i];
    }
}

extern "C" void kernel_launch(void* const* d_in, const int* in_sizes, int n_in,
                              void* d_out, int out_size, void* d_ws, size_t ws_size,
                              hipStream_t stream) {
    const float*  x       = (const float*)d_in[0];
    const float4* data    = (const float4*)d_in[1];
    const float*  scales  = (const float*)d_in[2];
    const int*    offsets = (const int*)d_in[3];
    float*        out     = (float*)d_out;

    const int N = in_sizes[0];           // x is [N,1]
    const int nblocks = (N + PPB - 1) / PPB;
    grid_enc_kernel<<<nblocks, BLOCK, 0, stream>>>(x, data, scales, offsets, out, N);
}